// Round 8
// baseline (2947.721 us; speedup 1.0000x reference)
//
#include <hip/hip_runtime.h>
#include <hip/hip_bf16.h>
#include <stdint.h>

// ContextEncoder: 2-layer LSTM x2 sides, B=256 T=128 D=300 H=512, gather-last, @[1024,200].
// R15 = R14 (verified 2354us) with consumer redundancy HALVED via 512-thread blocks.
// Linear model from R11/R14: step = 6.3us fixed + 0.875us/MB uncached exchange traffic
// (~1.1 TB/s byte cap). Volume is redundancy-bound: 8 consumer blocks re-read each
// group's h-tile. New geometry: 8 waves/block (2/SIMD @ ~204 VGPR, launch_bounds(512,2)),
// block holds 128 h-cols (8 waves x 16); layer = 2 sides x 16 groups(16 rows) x 4 colblks
// = 128 blocks; both layers = 256 blocks = 256 CUs. Consumers/group 8 -> 4, exchange
// read volume 8 -> 4 MB/step. Protocol primitives byte-identical to R14:
//   read  = global_load_dwordx4 sc0 sc1, one vmcnt(0) + sched_barrier, LDS XOR swizzle
//   write = global_store_dwordx4 sc0 sc1 on (ln&7)==0 (8 cols packed via 3 shfls)
//   release = vmcnt(0) + __syncthreads + RELEASE per-group flag add (target 4*t)
//   spin  = wave 0 only, relaxed agent load + s_sleep(2); 256-B flag slots
// Layer pipeline unchanged: layer0(chunk c) || layer1(chunk c-1), TC=8.

using short4_t = __attribute__((ext_vector_type(4))) short;
using short8_t = __attribute__((ext_vector_type(8))) short;
using f32x4    = __attribute__((ext_vector_type(4))) float;
using i32x4    = __attribute__((ext_vector_type(4))) int;

#define B_   256
#define T_   128
#define Draw 300
#define Dp   320
#define H_   512
#define G4   2048
#define TC   8           // time-chunk length
#define MC   (TC * 256)  // rows per chunk (2048)
#define NC   (T_ / TC)   // 16 chunks
#define FLAG_STRIDE 64   // unsigned per flag slot (256 B)

__device__ __forceinline__ short f2bf(float x){
  union { float f; unsigned u; } v; v.f = x;
  unsigned r = (v.u + 0x7FFFu + ((v.u >> 16) & 1u)) >> 16;
  return (short)r;
}
__device__ __forceinline__ float bf2f(short b){
  union { unsigned u; float f; } v; v.u = ((unsigned)(unsigned short)b) << 16;
  return v.f;
}
__device__ __forceinline__ float sigf(float x){ return 1.f / (1.f + __expf(-x)); }
__device__ __forceinline__ float tanh_f(float x){
  x = fmaxf(-15.f, fminf(15.f, x));
  float e = __expf(-2.f * x);
  return (1.f - e) / (1.f + e);
}
__device__ __forceinline__ void gload_lds16(const void* g, void* l){
  __builtin_amdgcn_global_load_lds((const __attribute__((address_space(1))) void*)g,
                                   (__attribute__((address_space(3))) void*)l, 16, 0, 0);
}

// ---------- prep: pad/cast one time-chunk of X into [2][tl*256+b][320] ----------
__global__ __launch_bounds__(256) void pad_x_chunk(const float* __restrict__ xl,
                                                   const float* __restrict__ xr,
                                                   short* __restrict__ xpadc, int t0)
{
  const int N = 2 * MC * Dp;
  for(int i = blockIdx.x * 256 + threadIdx.x; i < N; i += gridDim.x * 256){
    int side = i / (MC * Dp);
    int rem  = i - side * (MC * Dp);
    int row  = rem / Dp;
    int d    = rem - row * Dp;
    int tl = row >> 8, b = row & 255;
    const float* x = side ? xr : xl;
    float v = (d < Draw) ? x[((size_t)b * T_ + (t0 + tl)) * Draw + d] : 0.f;
    xpadc[i] = f2bf(v);
  }
}

// ---------- prep: W[k][n] (f32) -> WT[n][k] (bf16), zero-pad k>=krows ----------
__global__ __launch_bounds__(256) void transpose_w(const float* __restrict__ in,
                                                   short* __restrict__ out,
                                                   int row_off, int krows, int K)
{
  __shared__ float tile[32][33];
  int k0 = blockIdx.x * 32, n0 = blockIdx.y * 32;
  int tx = threadIdx.x & 31, ty = threadIdx.x >> 5;   // ty 0..7
  #pragma unroll
  for(int p = 0; p < 4; p++){
    int k = k0 + ty + p * 8;
    float v = (k < krows) ? in[(size_t)(k + row_off) * G4 + (n0 + tx)] : 0.f;
    tile[ty + p * 8][tx] = v;
  }
  __syncthreads();
  #pragma unroll
  for(int p = 0; p < 4; p++){
    int n = n0 + ty + p * 8;
    out[(size_t)n * K + k0 + tx] = f2bf(tile[tx][ty + p * 8]);
  }
}

// ---------- chunk GEMM: Z[m][n] = A[m][:K] @ W^T[n][:K] + bias[n], both sides ----------
__global__ __launch_bounds__(256, 2) void gemm_zpre(
    const short* __restrict__ Al, const short* __restrict__ Ar,
    const short* __restrict__ Wl, const short* __restrict__ Wr,
    const float* __restrict__ bl, const float* __restrict__ br,
    short* __restrict__ Zl, short* __restrict__ Zr, int K)
{
  __shared__ short As[8192];
  __shared__ short Bs[8192];
  const int side = blockIdx.z;
  const short* A = side ? Ar : Al;
  const short* W = side ? Wr : Wl;
  const float* bias = side ? br : bl;
  short* Zo = side ? Zr : Zl;
  const int m0 = blockIdx.x * 128, n0 = blockIdx.y * 128;
  const int tid = threadIdx.x, l = tid & 63, w = tid >> 6;
  const int wm = w & 1, wn = w >> 1;
  const int ln = l & 15, lq = l >> 4;

  f32x4 acc[4][4];
  const f32x4 z4 = {0.f, 0.f, 0.f, 0.f};
  #pragma unroll
  for(int i = 0; i < 4; i++)
    #pragma unroll
    for(int j = 0; j < 4; j++) acc[i][j] = z4;

  for(int k0 = 0; k0 < K; k0 += 64){
    __syncthreads();
    #pragma unroll
    for(int i = 0; i < 4; i++){
      int qb = w * 256 + i * 64;          // wave-uniform LDS chunk base
      int q  = qb + l;
      int row = q >> 3, c = q & 7, cs = c ^ (row & 7);   // XOR swizzle
      gload_lds16(A + (size_t)(m0 + row) * K + k0 + cs * 8, As + qb * 8);
      gload_lds16(W + (size_t)(n0 + row) * K + k0 + cs * 8, Bs + qb * 8);
    }
    __syncthreads();
    #pragma unroll
    for(int kt = 0; kt < 2; kt++){
      short8_t af[4], bf[4];
      #pragma unroll
      for(int i = 0; i < 4; i++){
        int mr = wm * 64 + i * 16 + ln;
        int nr = wn * 64 + i * 16 + ln;
        int cw = kt * 4 + lq;
        af[i] = *(const short8_t*)(As + (mr * 8 + (cw ^ (mr & 7))) * 8);
        bf[i] = *(const short8_t*)(Bs + (nr * 8 + (cw ^ (nr & 7))) * 8);
      }
      #pragma unroll
      for(int i = 0; i < 4; i++)
        #pragma unroll
        for(int j = 0; j < 4; j++)
          acc[i][j] = __builtin_amdgcn_mfma_f32_16x16x32_bf16(af[i], bf[j], acc[i][j], 0, 0, 0);
    }
  }
  #pragma unroll
  for(int j = 0; j < 4; j++){
    int n = n0 + wn * 64 + j * 16 + ln;
    float bv = bias[n];
    int gn = (n0 >> 4) + wn * 4 + j;
    #pragma unroll
    for(int i = 0; i < 4; i++){
      int gm = (m0 >> 4) + wm * 4 + i;
      short4_t sv;
      #pragma unroll
      for(int r = 0; r < 4; r++) sv[r] = f2bf(acc[i][j][r] + bv);
      *(short4_t*)(Zo + ((size_t)(gm * 128 + gn) * 64 + l) * 4) = sv;
    }
  }
}

// ---------- dual-layer recurrent chunk kernel: TC steps, both layers, both sides ----------
// 256 blocks x 512 threads: lay(2) x side(2) x group(16, 16 rows) x colblk(4, 128 cols).
// Wave w (0..7) owns 16 h-cols (hc = cb*128 + w*16) x 4 gates; Bf[4][16] resident.
__global__ __launch_bounds__(512, 2) void lstm_rec_dual(
    const short* __restrict__ Z0l, const short* __restrict__ Z0r,
    const short* __restrict__ Z1l, const short* __restrict__ Z1r,
    const short* __restrict__ Wt0l, const short* __restrict__ Wt0r,
    const short* __restrict__ Wt1l, const short* __restrict__ Wt1r,
    short* __restrict__ h0l, short* __restrict__ h0r,
    short* __restrict__ h1l, short* __restrict__ h1r,
    float* __restrict__ cstate,
    const int* __restrict__ lenl, const int* __restrict__ lenr,
    float* __restrict__ ctx,
    unsigned* __restrict__ flags, int t0, int has0, int has1)
{
  __shared__ short hlds[16 * 512];   // h(t-1) staging: 16 rows x 512 cols bf16 (16 KB)
  const int blk = blockIdx.x;
  const int lay  = blk >> 7;
  const int side = (blk >> 6) & 1;
  const int g    = (blk >> 2) & 15;
  const int cb   = blk & 3;
  if(lay ? (!has1) : (!has0)) return;
  const int tid = threadIdx.x, l = tid & 63, w = tid >> 6;   // w 0..7
  const int ln = l & 15, lq = l >> 4;
  const short* Z  = lay ? (side ? Z1r : Z1l) : (side ? Z0r : Z0l);
  const short* Wt = lay ? (side ? Wt1r : Wt1l) : (side ? Wt0r : Wt0l);
  short* hseq = lay ? (side ? h1r : h1l) : (side ? h0r : h0l);
  const int mask  = lay ? 1 : (TC - 1);
  const int tbase = lay ? (t0 - TC) : t0;
  const int* len = lay ? (side ? lenr : lenl) : nullptr;
  unsigned* flag = flags + (size_t)((lay * 2 + side) * 16 + g) * FLAG_STRIDE;
  const int hc = cb * 128 + w * 16;          // this wave's h-col base
  const int rbase = g * 16;                  // 16 batch rows per group

  // Preload W_h B-fragments (loop-invariant): lane holds B[k][n], n = hc + ln.
  short8_t Bf[4][16];
  #pragma unroll
  for(int gate = 0; gate < 4; gate++){
    const short* wp = Wt + (size_t)(gate * 512 + hc + ln) * 512 + lq * 8;
    #pragma unroll
    for(int kt = 0; kt < 16; kt++)
      Bf[gate][kt] = *(const short8_t*)(wp + kt * 32);
  }

  // c-state: rows rbase + lq*4 + r, col hc + ln
  float* cptr = cstate + ((size_t)((lay * 2 + side) * 256 + rbase + lq * 4) * 512) + hc + ln;
  float cst[4];
  if(tbase == 0){
    #pragma unroll
    for(int r = 0; r < 4; r++) cst[r] = 0.f;
  } else {
    #pragma unroll
    for(int r = 0; r < 4; r++) cst[r] = cptr[(size_t)r * 512];
  }

  for(int tl = 0; tl < TC; tl++){
    const int t = tbase + tl;
    // Z prefetch (cached loads, issued before the spin). gm-tile = tl*16 + g.
    short4_t zv[4];
    {
      const int gm = tl * 16 + g;
      #pragma unroll
      for(int gate = 0; gate < 4; gate++){
        int gn = gate * 32 + cb * 8 + w;
        zv[gate] = *(const short4_t*)(Z + ((size_t)(gm * 128 + gn) * 64 + l) * 4);
      }
    }
    if(t > 0){
      const unsigned target = 4u * (unsigned)t;
      if(w == 0){
        while(__hip_atomic_load(flag, __ATOMIC_RELAXED, __HIP_MEMORY_SCOPE_AGENT) < target)
          __builtin_amdgcn_s_sleep(2);
      }
      __syncthreads();
      __atomic_signal_fence(__ATOMIC_ACQUIRE);
      // cooperative copy of h(t-1) tile [16 rows x 512 cols] into LDS.
      // 16B coherent loads (sc0 sc1), 2 per thread, one vmcnt(0) drain, then LDS
      // writes with XOR slot swizzle (sp = s ^ (row & 7)).
      const char* hsrc = (const char*)
          (hseq + ((size_t)(((t - 1) & mask) * 256 + rbase)) * 512);
      i32x4 tmp[2];
      #pragma unroll
      for(int it = 0; it < 2; it++){
        int gidx = it * 512 + tid;          // 0..1023 granules of 16B
        int row = gidx >> 6, s = gidx & 63; // 64 granules per 1KB row
        const void* src = hsrc + (size_t)row * 1024 + (size_t)s * 16;
        asm volatile("global_load_dwordx4 %0, %1, off sc0 sc1"
                     : "=v"(tmp[it]) : "v"(src));
      }
      asm volatile("s_waitcnt vmcnt(0)" ::: "memory");
      __builtin_amdgcn_sched_barrier(0);
      #pragma unroll
      for(int it = 0; it < 2; it++){
        int gidx = it * 512 + tid;
        int row = gidx >> 6, s = gidx & 63;
        int sp = s ^ (row & 7);
        *(i32x4*)(hlds + row * 512 + sp * 8) = tmp[it];
      }
      __syncthreads();
    }

    // acc init from Z, MFMA over 16 k-tiles
    f32x4 acc[4];
    #pragma unroll
    for(int gate = 0; gate < 4; gate++)
      #pragma unroll
      for(int r = 0; r < 4; r++) acc[gate][r] = bf2f(zv[gate][r]);
    if(t > 0){
      short8_t af[16];
      #pragma unroll
      for(int kt = 0; kt < 16; kt++){
        int sp = (kt * 4 + lq) ^ (ln & 7);
        af[kt] = *(const short8_t*)(hlds + ln * 512 + sp * 8);
      }
      #pragma unroll
      for(int kt = 0; kt < 16; kt++)
        #pragma unroll
        for(int gate = 0; gate < 4; gate++)
          acc[gate] = __builtin_amdgcn_mfma_f32_16x16x32_bf16(af[kt], Bf[gate][kt],
                                                              acc[gate], 0, 0, 0);
    }
    // activations (gate order i, j, f, o; forget bias +1)
    float hv[4];
    #pragma unroll
    for(int r = 0; r < 4; r++){
      float iv = sigf(acc[0][r]);
      float jv = tanh_f(acc[1][r]);
      float fv = sigf(acc[2][r] + 1.0f);
      float ov = sigf(acc[3][r]);
      float c  = cst[r] * fv + iv * jv;
      cst[r] = c;
      hv[r] = tanh_f(c) * ov;
    }
    // publish h into ring slot t: pack 8 cols into 16B on lanes (ln&7)==0,
    // coherent store; drained by the vmcnt(0) below before the RELEASE flag add.
    {
      short* hrow = hseq + ((size_t)((t & mask) * 256 + rbase + lq * 4)) * 512 + hc + ln;
      #pragma unroll
      for(int r = 0; r < 4; r++){
        unsigned lo = (unsigned short)f2bf(hv[r]);
        unsigned hi = (unsigned short)f2bf(__shfl_xor(hv[r], 1, 64));
        unsigned pk  = lo | (hi << 16);            // cols (ln, ln^1), even ln
        unsigned pkB = __shfl_xor(pk, 2, 64);      // cols (ln^2, ln^3)
        unsigned pkC = __shfl_xor(pk, 4, 64);      // cols (ln^4, ln^5)
        unsigned pkD = __shfl_xor(pkB, 4, 64);     // cols (ln^6, ln^7)
        if((ln & 7) == 0){
          i32x4 sv; sv[0] = (int)pk; sv[1] = (int)pkB;
          sv[2] = (int)pkC; sv[3] = (int)pkD;
          asm volatile("global_store_dwordx4 %0, %1, off sc0 sc1"
                       :: "v"(hrow + (size_t)r * 512), "v"(sv) : "memory");
        }
      }
    }
    if(len){ // layer 1: gather last valid h into ctx (fp32; read next dispatch)
      #pragma unroll
      for(int r = 0; r < 4; r++){
        int b = rbase + lq * 4 + r;
        if(len[b] - 1 == t)
          ctx[(size_t)b * 1024 + side * 512 + hc + ln] = hv[r];
      }
    }
    // release: drain publish stores, sync block, one RELEASE flag add.
    __atomic_signal_fence(__ATOMIC_SEQ_CST);
    asm volatile("s_waitcnt vmcnt(0)" ::: "memory");
    __syncthreads();
    if(tid == 0)
      __hip_atomic_fetch_add(flag, 1u, __ATOMIC_RELEASE, __HIP_MEMORY_SCOPE_AGENT);
  }
  // persist c-state for next chunk
  #pragma unroll
  for(int r = 0; r < 4; r++) cptr[(size_t)r * 512] = cst[r];
}

// ---------- final: out[256][200] = ctx[256][1024] @ W[1024][200] (fp32) ----------
__global__ __launch_bounds__(256) void final_mm(const float* __restrict__ ctx,
                                                const float* __restrict__ W,
                                                float* __restrict__ out)
{
  __shared__ float cs[4][1024];
  const int tid = threadIdx.x;
  const int b0 = blockIdx.x * 4;
  for(int i = tid; i < 4 * 1024; i += 256)
    cs[i >> 10][i & 1023] = ctx[(size_t)b0 * 1024 + i];
  __syncthreads();
  if(tid < 200){
    float a0 = 0, a1 = 0, a2 = 0, a3 = 0;
    for(int k = 0; k < 1024; k++){
      float wv = W[k * 200 + tid];
      a0 += cs[0][k] * wv; a1 += cs[1][k] * wv;
      a2 += cs[2][k] * wv; a3 += cs[3][k] * wv;
    }
    out[(size_t)(b0 + 0) * 200 + tid] = a0;
    out[(size_t)(b0 + 1) * 200 + tid] = a1;
    out[(size_t)(b0 + 2) * 200 + tid] = a2;
    out[(size_t)(b0 + 3) * 200 + tid] = a3;
  }
}

extern "C" void kernel_launch(void* const* d_in, const int* in_sizes, int n_in,
                              void* d_out, int out_size, void* d_ws, size_t ws_size,
                              hipStream_t stream)
{
  (void)in_sizes; (void)n_in; (void)out_size; (void)ws_size;
  const float* xl   = (const float*)d_in[0];
  const float* xr   = (const float*)d_in[1];
  const int*   lenl = (const int*)  d_in[2];
  const int*   lenr = (const int*)  d_in[3];
  const float* lW0  = (const float*)d_in[4];
  const float* lb0  = (const float*)d_in[5];
  const float* lW1  = (const float*)d_in[6];
  const float* lb1  = (const float*)d_in[7];
  const float* rW0  = (const float*)d_in[8];
  const float* rb0  = (const float*)d_in[9];
  const float* rW1  = (const float*)d_in[10];
  const float* rb1  = (const float*)d_in[11];
  const float* tW   = (const float*)d_in[12];
  float* out = (float*)d_out;
  char* ws = (char*)d_ws;

  constexpr size_t SZ_WXT0 = (size_t)2048 * Dp * 2;       // 1.31 MB
  constexpr size_t SZ_WT   = (size_t)2048 * 512 * 2;      // 2.10 MB
  constexpr size_t SZ_XPC  = (size_t)2 * MC * Dp * 2;     // 2.62 MB
  constexpr size_t SZ_ZPRE = (size_t)MC * 2048 * 2;       // 8.39 MB per side per layer
  constexpr size_t SZ_H0   = (size_t)TC * 256 * 512 * 2;  // 2.10 MB per side
  constexpr size_t SZ_H1   = (size_t)2 * 256 * 512 * 2;   // 0.52 MB per side
  constexpr size_t SZ_CST  = (size_t)2 * 2 * 256 * 512 * 4; // 2.10 MB
  constexpr size_t SZ_CTX  = (size_t)256 * 1024 * 4;      // 1.05 MB
  constexpr size_t SZ_FLAGS = (size_t)64 * FLAG_STRIDE * 4; // 16 KB

  size_t off = 0;
  auto carve = [&](size_t sz){ size_t o = off; off += (sz + 255) & ~(size_t)255; return o; };
  size_t o_wxt0_l = carve(SZ_WXT0), o_wxt0_r = carve(SZ_WXT0);
  size_t o_wht0_l = carve(SZ_WT),   o_wht0_r = carve(SZ_WT);
  size_t o_wxt1_l = carve(SZ_WT),   o_wxt1_r = carve(SZ_WT);
  size_t o_wht1_l = carve(SZ_WT),   o_wht1_r = carve(SZ_WT);
  size_t o_xpc    = carve(SZ_XPC);
  size_t o_zp0_l  = carve(SZ_ZPRE), o_zp0_r  = carve(SZ_ZPRE);
  size_t o_zp1_l  = carve(SZ_ZPRE), o_zp1_r  = carve(SZ_ZPRE);
  size_t o_h0_l   = carve(SZ_H0),   o_h0_r   = carve(SZ_H0);
  size_t o_h1_l   = carve(SZ_H1),   o_h1_r   = carve(SZ_H1);
  size_t o_cst    = carve(SZ_CST);
  size_t o_ctx    = carve(SZ_CTX);
  size_t o_flags  = carve(SZ_FLAGS);
  // total ~57 MB

  short* wxt0_l = (short*)(ws + o_wxt0_l);
  short* wxt0_r = (short*)(ws + o_wxt0_r);
  short* wht0_l = (short*)(ws + o_wht0_l);
  short* wht0_r = (short*)(ws + o_wht0_r);
  short* wxt1_l = (short*)(ws + o_wxt1_l);
  short* wxt1_r = (short*)(ws + o_wxt1_r);
  short* wht1_l = (short*)(ws + o_wht1_l);
  short* wht1_r = (short*)(ws + o_wht1_r);
  short* xpc_l  = (short*)(ws + o_xpc);
  short* xpc_r  = xpc_l + (size_t)MC * Dp;
  short* zp0_l  = (short*)(ws + o_zp0_l);
  short* zp0_r  = (short*)(ws + o_zp0_r);
  short* zp1_l  = (short*)(ws + o_zp1_l);
  short* zp1_r  = (short*)(ws + o_zp1_r);
  short* h0_l   = (short*)(ws + o_h0_l);
  short* h0_r   = (short*)(ws + o_h0_r);
  short* h1_l   = (short*)(ws + o_h1_l);
  short* h1_r   = (short*)(ws + o_h1_r);
  float* cst    = (float*)(ws + o_cst);
  float* ctx    = (float*)(ws + o_ctx);
  unsigned* flags = (unsigned*)(ws + o_flags);

  hipMemsetAsync(flags, 0, SZ_FLAGS, stream);

  transpose_w<<<dim3(Dp / 32, 64), 256, 0, stream>>>(lW0, wxt0_l,   0, Draw, Dp);
  transpose_w<<<dim3(Dp / 32, 64), 256, 0, stream>>>(rW0, wxt0_r,   0, Draw, Dp);
  transpose_w<<<dim3(16, 64),      256, 0, stream>>>(lW0, wht0_l, 300,  512, 512);
  transpose_w<<<dim3(16, 64),      256, 0, stream>>>(rW0, wht0_r, 300,  512, 512);
  transpose_w<<<dim3(16, 64),      256, 0, stream>>>(lW1, wxt1_l,   0,  512, 512);
  transpose_w<<<dim3(16, 64),      256, 0, stream>>>(rW1, wxt1_r,   0,  512, 512);
  transpose_w<<<dim3(16, 64),      256, 0, stream>>>(lW1, wht1_l, 512,  512, 512);
  transpose_w<<<dim3(16, 64),      256, 0, stream>>>(rW1, wht1_r, 512,  512, 512);

  for(int c = 0; c < NC; c++){
    const int t0 = c * TC;
    pad_x_chunk<<<2048, 256, 0, stream>>>(xl, xr, xpc_l, t0);
    // layer 0: zpre0(c) = xchunk @ Wx0 + b0
    gemm_zpre<<<dim3(MC / 128, 16, 2), 256, 0, stream>>>(xpc_l, xpc_r, wxt0_l, wxt0_r,
                                                         lb0, rb0, zp0_l, zp0_r, Dp);
    // layer 1: zpre1(c-1) = h0(c-1) @ Wx1 + b1 (h0 ring holds chunk c-1)
    if(c > 0)
      gemm_zpre<<<dim3(MC / 128, 16, 2), 256, 0, stream>>>(h0_l, h0_r, wxt1_l, wxt1_r,
                                                           lb1, rb1, zp1_l, zp1_r, 512);
    // dual: layer0 on chunk c || layer1 on chunk c-1
    lstm_rec_dual<<<256, 512, 0, stream>>>(zp0_l, zp0_r, zp1_l, zp1_r,
                                           wht0_l, wht0_r, wht1_l, wht1_r,
                                           h0_l, h0_r, h1_l, h1_r,
                                           cst, lenl, lenr, ctx, flags,
                                           t0, 1, c > 0 ? 1 : 0);
  }
  // tail: layer1 on chunk NC-1
  gemm_zpre<<<dim3(MC / 128, 16, 2), 256, 0, stream>>>(h0_l, h0_r, wxt1_l, wxt1_r,
                                                       lb1, rb1, zp1_l, zp1_r, 512);
  lstm_rec_dual<<<256, 512, 0, stream>>>(zp0_l, zp0_r, zp1_l, zp1_r,
                                         wht0_l, wht0_r, wht1_l, wht1_r,
                                         h0_l, h0_r, h1_l, h1_r,
                                         cst, lenl, lenr, ctx, flags,
                                         NC * TC, 0, 1);

  final_mm<<<64, 256, 0, stream>>>(ctx, tW, out);
}

// Round 9
// 2323.303 us; speedup vs baseline: 1.2688x; 1.2688x over previous
//
#include <hip/hip_runtime.h>
#include <hip/hip_bf16.h>
#include <stdint.h>

// ContextEncoder: 2-layer LSTM x2 sides, B=256 T=128 D=300 H=512, gather-last, @[1024,200].
// R16 = R14's verified rec kernel (byte-identical) + host-side dispatch-chain slimming.
// R15 post-mortem: 512-thread blocks are structurally impossible (Bf residency ~460
// regs/wave => 1 wave/SIMD max; 8-wave blocks need 2/SIMD -> compiler clamps VGPR to
// 128 and spills Bf to scratch: FETCH 162MB, 145us/dispatch). colblks=8 and the
// 8 MB/step exchange volume are forced; R14's 13.3us/step = 6.3 fixed + ~7 traffic
// at the ~1.1 TB/s uncached byte-rate is the exchange floor.
// R16 removes the OTHER cost: ~540us of serialized small-dispatch overhead.
//   1. pad ALL x upfront (1 dispatch, 42 MB) -- was 16 in-loop dispatches.
//   2. gemm0 batched 2 chunks (M=4096, 8 dispatches) -- was 16; rec reads zpre0 with
//      a (c&1)*MC*2048 pointer offset (kernel unchanged).
//   3. lstm_rec_dual identical to R14: 16B sc0/sc1 exchange, aggregated 256-B flags,
//      wave-0 spin, vmcnt(0)+RELEASE, TC=8, layer0(c) || layer1(c-1).

using short4_t = __attribute__((ext_vector_type(4))) short;
using short8_t = __attribute__((ext_vector_type(8))) short;
using f32x4    = __attribute__((ext_vector_type(4))) float;
using i32x4    = __attribute__((ext_vector_type(4))) int;

#define B_   256
#define T_   128
#define Draw 300
#define Dp   320
#define H_   512
#define G4   2048
#define TC   8           // time-chunk length
#define MC   (TC * 256)  // rows per chunk (2048)
#define NC   (T_ / TC)   // 16 chunks
#define FLAG_STRIDE 64   // unsigned per flag slot (256 B)

__device__ __forceinline__ short f2bf(float x){
  union { float f; unsigned u; } v; v.f = x;
  unsigned r = (v.u + 0x7FFFu + ((v.u >> 16) & 1u)) >> 16;
  return (short)r;
}
__device__ __forceinline__ float bf2f(short b){
  union { unsigned u; float f; } v; v.u = ((unsigned)(unsigned short)b) << 16;
  return v.f;
}
__device__ __forceinline__ float sigf(float x){ return 1.f / (1.f + __expf(-x)); }
__device__ __forceinline__ float tanh_f(float x){
  x = fmaxf(-15.f, fminf(15.f, x));
  float e = __expf(-2.f * x);
  return (1.f - e) / (1.f + e);
}
__device__ __forceinline__ void gload_lds16(const void* g, void* l){
  __builtin_amdgcn_global_load_lds((const __attribute__((address_space(1))) void*)g,
                                   (__attribute__((address_space(3))) void*)l, 16, 0, 0);
}

// ---------- prep: pad/cast ALL of X into [2][t*256+b][320] (one shot) ----------
__global__ __launch_bounds__(256) void pad_x_all(const float* __restrict__ xl,
                                                 const float* __restrict__ xr,
                                                 short* __restrict__ xpadc)
{
  const int NR = T_ * 256;             // 32768 rows per side
  const int N = 2 * NR * Dp;
  for(int i = blockIdx.x * 256 + threadIdx.x; i < N; i += gridDim.x * 256){
    int side = i / (NR * Dp);
    int rem  = i - side * (NR * Dp);
    int row  = rem / Dp;
    int d    = rem - row * Dp;
    int t = row >> 8, b = row & 255;
    const float* x = side ? xr : xl;
    float v = (d < Draw) ? x[((size_t)b * T_ + t) * Draw + d] : 0.f;
    xpadc[i] = f2bf(v);
  }
}

// ---------- prep: W[k][n] (f32) -> WT[n][k] (bf16), zero-pad k>=krows ----------
__global__ __launch_bounds__(256) void transpose_w(const float* __restrict__ in,
                                                   short* __restrict__ out,
                                                   int row_off, int krows, int K)
{
  __shared__ float tile[32][33];
  int k0 = blockIdx.x * 32, n0 = blockIdx.y * 32;
  int tx = threadIdx.x & 31, ty = threadIdx.x >> 5;   // ty 0..7
  #pragma unroll
  for(int p = 0; p < 4; p++){
    int k = k0 + ty + p * 8;
    float v = (k < krows) ? in[(size_t)(k + row_off) * G4 + (n0 + tx)] : 0.f;
    tile[ty + p * 8][tx] = v;
  }
  __syncthreads();
  #pragma unroll
  for(int p = 0; p < 4; p++){
    int n = n0 + ty + p * 8;
    out[(size_t)n * K + k0 + tx] = f2bf(tile[tx][ty + p * 8]);
  }
}

// ---------- chunk GEMM: Z[m][n] = A[m][:K] @ W^T[n][:K] + bias[n], both sides ----------
// Output in MFMA-C-fragment tiled layout: tile (gm=m>>4, gn=n>>4), lane l holds rows
// (l>>4)*4+r, col l&15, stored as short4 at Z[((gm*128+gn)*64+l)*4]. M = 128*gridDim.x.
__global__ __launch_bounds__(256, 2) void gemm_zpre(
    const short* __restrict__ Al, const short* __restrict__ Ar,
    const short* __restrict__ Wl, const short* __restrict__ Wr,
    const float* __restrict__ bl, const float* __restrict__ br,
    short* __restrict__ Zl, short* __restrict__ Zr, int K)
{
  __shared__ short As[8192];
  __shared__ short Bs[8192];
  const int side = blockIdx.z;
  const short* A = side ? Ar : Al;
  const short* W = side ? Wr : Wl;
  const float* bias = side ? br : bl;
  short* Zo = side ? Zr : Zl;
  const int m0 = blockIdx.x * 128, n0 = blockIdx.y * 128;
  const int tid = threadIdx.x, l = tid & 63, w = tid >> 6;
  const int wm = w & 1, wn = w >> 1;
  const int ln = l & 15, lq = l >> 4;

  f32x4 acc[4][4];
  const f32x4 z4 = {0.f, 0.f, 0.f, 0.f};
  #pragma unroll
  for(int i = 0; i < 4; i++)
    #pragma unroll
    for(int j = 0; j < 4; j++) acc[i][j] = z4;

  for(int k0 = 0; k0 < K; k0 += 64){
    __syncthreads();
    #pragma unroll
    for(int i = 0; i < 4; i++){
      int qb = w * 256 + i * 64;          // wave-uniform LDS chunk base
      int q  = qb + l;
      int row = q >> 3, c = q & 7, cs = c ^ (row & 7);   // XOR swizzle
      gload_lds16(A + (size_t)(m0 + row) * K + k0 + cs * 8, As + qb * 8);
      gload_lds16(W + (size_t)(n0 + row) * K + k0 + cs * 8, Bs + qb * 8);
    }
    __syncthreads();
    #pragma unroll
    for(int kt = 0; kt < 2; kt++){
      short8_t af[4], bf[4];
      #pragma unroll
      for(int i = 0; i < 4; i++){
        int mr = wm * 64 + i * 16 + ln;
        int nr = wn * 64 + i * 16 + ln;
        int cw = kt * 4 + lq;
        af[i] = *(const short8_t*)(As + (mr * 8 + (cw ^ (mr & 7))) * 8);
        bf[i] = *(const short8_t*)(Bs + (nr * 8 + (cw ^ (nr & 7))) * 8);
      }
      #pragma unroll
      for(int i = 0; i < 4; i++)
        #pragma unroll
        for(int j = 0; j < 4; j++)
          acc[i][j] = __builtin_amdgcn_mfma_f32_16x16x32_bf16(af[i], bf[j], acc[i][j], 0, 0, 0);
    }
  }
  #pragma unroll
  for(int j = 0; j < 4; j++){
    int n = n0 + wn * 64 + j * 16 + ln;
    float bv = bias[n];
    int gn = (n0 >> 4) + wn * 4 + j;
    #pragma unroll
    for(int i = 0; i < 4; i++){
      int gm = (m0 >> 4) + wm * 4 + i;
      short4_t sv;
      #pragma unroll
      for(int r = 0; r < 4; r++) sv[r] = f2bf(acc[i][j][r] + bv);
      *(short4_t*)(Zo + ((size_t)(gm * 128 + gn) * 64 + l) * 4) = sv;
    }
  }
}

// ---------- dual-layer recurrent chunk kernel: TC steps, both layers, both sides ----------
// 256 blocks: lay(2: layer0 chunk c | layer1 chunk c-1) x side(2) x group(8, 32 rows)
// x colblk(8, 64 h-cols). Wave w owns 16 h-cols x 4 gates (Bf[4][16] resident).
// Two row-sets (rs=0,1) share af/acc registers sequentially.  [VERIFIED R14 KERNEL]
__global__ __launch_bounds__(256, 1) void lstm_rec_dual(
    const short* __restrict__ Z0l, const short* __restrict__ Z0r,
    const short* __restrict__ Z1l, const short* __restrict__ Z1r,
    const short* __restrict__ Wt0l, const short* __restrict__ Wt0r,
    const short* __restrict__ Wt1l, const short* __restrict__ Wt1r,
    short* __restrict__ h0l, short* __restrict__ h0r,
    short* __restrict__ h1l, short* __restrict__ h1r,
    float* __restrict__ cstate,
    const int* __restrict__ lenl, const int* __restrict__ lenr,
    float* __restrict__ ctx,
    unsigned* __restrict__ flags, int t0, int has0, int has1)
{
  __shared__ short hlds[32 * 512];   // h(t-1) staging: 32 rows x 512 cols bf16 (32 KB)
  const int blk = blockIdx.x;
  const int lay  = blk >> 7;
  const int side = (blk >> 6) & 1;
  const int g    = (blk >> 3) & 7;
  const int cb   = blk & 7;
  if(lay ? (!has1) : (!has0)) return;
  const int tid = threadIdx.x, l = tid & 63, w = tid >> 6;
  const int ln = l & 15, lq = l >> 4;
  const short* Z  = lay ? (side ? Z1r : Z1l) : (side ? Z0r : Z0l);
  const short* Wt = lay ? (side ? Wt1r : Wt1l) : (side ? Wt0r : Wt0l);
  short* hseq = lay ? (side ? h1r : h1l) : (side ? h0r : h0l);
  const int mask  = lay ? 1 : (TC - 1);
  const int tbase = lay ? (t0 - TC) : t0;
  const int* len = lay ? (side ? lenr : lenl) : nullptr;
  unsigned* flag = flags + (size_t)((lay * 2 + side) * 8 + g) * FLAG_STRIDE;
  const int hc = cb * 64 + w * 16;           // this wave's h-col base
  const int rbase = g * 32;                  // 32 batch rows per group

  // Preload W_h B-fragments (loop-invariant): lane holds B[k][n], n = hc + ln.
  short8_t Bf[4][16];
  #pragma unroll
  for(int gate = 0; gate < 4; gate++){
    const short* wp = Wt + (size_t)(gate * 512 + hc + ln) * 512 + lq * 8;
    #pragma unroll
    for(int kt = 0; kt < 16; kt++)
      Bf[gate][kt] = *(const short8_t*)(wp + kt * 32);
  }

  // c-state: rows rbase + rs*16 + lq*4 + r, col hc + ln
  float* cptr = cstate + ((size_t)((lay * 2 + side) * 256 + rbase + lq * 4) * 512) + hc + ln;
  float cst[2][4];
  if(tbase == 0){
    #pragma unroll
    for(int rs = 0; rs < 2; rs++)
      #pragma unroll
      for(int r = 0; r < 4; r++) cst[rs][r] = 0.f;
  } else {
    #pragma unroll
    for(int rs = 0; rs < 2; rs++)
      #pragma unroll
      for(int r = 0; r < 4; r++) cst[rs][r] = cptr[(size_t)(rs * 16 + r) * 512];
  }

  for(int tl = 0; tl < TC; tl++){
    const int t = tbase + tl;
    // Z prefetch (cached loads, issued before the spin). gm-tile = tl*16 + g*2 + rs.
    short4_t zv0[4], zv1[4];
    {
      const int gmb = tl * 16 + g * 2;
      #pragma unroll
      for(int gate = 0; gate < 4; gate++){
        int gn = gate * 32 + cb * 4 + w;
        zv0[gate] = *(const short4_t*)(Z + ((size_t)(gmb * 128 + gn) * 64 + l) * 4);
        zv1[gate] = *(const short4_t*)(Z + ((size_t)((gmb + 1) * 128 + gn) * 64 + l) * 4);
      }
    }
    if(t > 0){
      const unsigned target = 8u * (unsigned)t;
      if(w == 0){
        while(__hip_atomic_load(flag, __ATOMIC_RELAXED, __HIP_MEMORY_SCOPE_AGENT) < target)
          __builtin_amdgcn_s_sleep(2);
      }
      __syncthreads();
      __atomic_signal_fence(__ATOMIC_ACQUIRE);
      // cooperative copy of h(t-1) tile [32 rows x 512 cols] into LDS.
      // 16B coherent loads (sc0 sc1 -> bypass L1+L2, always fresh), 8 per thread,
      // one vmcnt(0) drain, then LDS writes with XOR slot swizzle (sp = s ^ (row&7)).
      const char* hsrc = (const char*)
          (hseq + ((size_t)(((t - 1) & mask) * 256 + rbase)) * 512);
      i32x4 tmp[8];
      #pragma unroll
      for(int it = 0; it < 8; it++){
        int gidx = it * 256 + tid;          // 0..2047 granules of 16B
        int row = gidx >> 6, s = gidx & 63; // 64 granules per 1KB row
        const void* src = hsrc + (size_t)row * 1024 + (size_t)s * 16;
        asm volatile("global_load_dwordx4 %0, %1, off sc0 sc1"
                     : "=v"(tmp[it]) : "v"(src));
      }
      asm volatile("s_waitcnt vmcnt(0)" ::: "memory");
      __builtin_amdgcn_sched_barrier(0);
      #pragma unroll
      for(int it = 0; it < 8; it++){
        int gidx = it * 256 + tid;
        int row = gidx >> 6, s = gidx & 63;
        int sp = s ^ (row & 7);
        *(i32x4*)(hlds + row * 512 + sp * 8) = tmp[it];
      }
      __syncthreads();
    }

    // ---- per-row-set body (literal RS keeps all indexing static) ----
#define ROWSET_BODY(RS, ZV)                                                          \
    {                                                                                \
      f32x4 acc[4];                                                                  \
      _Pragma("unroll")                                                              \
      for(int gate = 0; gate < 4; gate++)                                            \
        _Pragma("unroll")                                                            \
        for(int r = 0; r < 4; r++) acc[gate][r] = bf2f(ZV[gate][r]);                 \
      if(t > 0){                                                                     \
        short8_t af[16];                                                             \
        _Pragma("unroll")                                                            \
        for(int kt = 0; kt < 16; kt++){                                              \
          int sp = (kt * 4 + lq) ^ (ln & 7);                                         \
          af[kt] = *(const short8_t*)(hlds + (RS * 16 + ln) * 512 + sp * 8);         \
        }                                                                            \
        _Pragma("unroll")                                                            \
        for(int kt = 0; kt < 16; kt++)                                               \
          _Pragma("unroll")                                                          \
          for(int gate = 0; gate < 4; gate++)                                        \
            acc[gate] = __builtin_amdgcn_mfma_f32_16x16x32_bf16(af[kt], Bf[gate][kt],\
                                                                acc[gate], 0, 0, 0);  \
      }                                                                              \
      float hv[4];                                                                   \
      _Pragma("unroll")                                                              \
      for(int r = 0; r < 4; r++){                                                    \
        float iv = sigf(acc[0][r]);                                                  \
        float jv = tanh_f(acc[1][r]);                                                \
        float fv = sigf(acc[2][r] + 1.0f);                                           \
        float ov = sigf(acc[3][r]);                                                  \
        float c  = cst[RS][r] * fv + iv * jv;                                        \
        cst[RS][r] = c;                                                              \
        hv[r] = tanh_f(c) * ov;                                                      \
      }                                                                              \
      {                                                                              \
        short* hrow = hseq + ((size_t)((t & mask) * 256 + rbase + RS * 16 + lq * 4)) \
                      * 512 + hc + ln;                                               \
        _Pragma("unroll")                                                            \
        for(int r = 0; r < 4; r++){                                                  \
          unsigned lo = (unsigned short)f2bf(hv[r]);                                 \
          unsigned hi = (unsigned short)f2bf(__shfl_xor(hv[r], 1, 64));              \
          unsigned pk  = lo | (hi << 16);            /* cols (ln,ln+1), even ln */   \
          unsigned pkB = __shfl_xor(pk, 2, 64);      /* cols (ln+2,ln+3)        */   \
          unsigned pkC = __shfl_xor(pk, 4, 64);      /* cols (ln+4,ln+5)        */   \
          unsigned pkD = __shfl_xor(pkB, 4, 64);     /* cols (ln+6,ln+7)        */   \
          if((ln & 7) == 0){                                                         \
            i32x4 sv; sv[0] = (int)pk; sv[1] = (int)pkB;                             \
            sv[2] = (int)pkC; sv[3] = (int)pkD;                                      \
            asm volatile("global_store_dwordx4 %0, %1, off sc0 sc1"                  \
                         :: "v"(hrow + (size_t)r * 512), "v"(sv) : "memory");        \
          }                                                                          \
        }                                                                            \
      }                                                                              \
      if(len){                                                                       \
        _Pragma("unroll")                                                            \
        for(int r = 0; r < 4; r++){                                                  \
          int b = rbase + RS * 16 + lq * 4 + r;                                      \
          if(len[b] - 1 == t)                                                        \
            ctx[(size_t)b * 1024 + side * 512 + hc + ln] = hv[r];                    \
        }                                                                            \
      }                                                                              \
    }

    ROWSET_BODY(0, zv0)
    ROWSET_BODY(1, zv1)
#undef ROWSET_BODY

    // release: drain publish stores, sync block, one RELEASE flag add.
    __atomic_signal_fence(__ATOMIC_SEQ_CST);
    asm volatile("s_waitcnt vmcnt(0)" ::: "memory");
    __syncthreads();
    if(tid == 0)
      __hip_atomic_fetch_add(flag, 1u, __ATOMIC_RELEASE, __HIP_MEMORY_SCOPE_AGENT);
  }
  // persist c-state for next chunk
  #pragma unroll
  for(int rs = 0; rs < 2; rs++)
    #pragma unroll
    for(int r = 0; r < 4; r++)
      cptr[(size_t)(rs * 16 + r) * 512] = cst[rs][r];
}

// ---------- final: out[256][200] = ctx[256][1024] @ W[1024][200] (fp32) ----------
__global__ __launch_bounds__(256) void final_mm(const float* __restrict__ ctx,
                                                const float* __restrict__ W,
                                                float* __restrict__ out)
{
  __shared__ float cs[4][1024];
  const int tid = threadIdx.x;
  const int b0 = blockIdx.x * 4;
  for(int i = tid; i < 4 * 1024; i += 256)
    cs[i >> 10][i & 1023] = ctx[(size_t)b0 * 1024 + i];
  __syncthreads();
  if(tid < 200){
    float a0 = 0, a1 = 0, a2 = 0, a3 = 0;
    for(int k = 0; k < 1024; k++){
      float wv = W[k * 200 + tid];
      a0 += cs[0][k] * wv; a1 += cs[1][k] * wv;
      a2 += cs[2][k] * wv; a3 += cs[3][k] * wv;
    }
    out[(size_t)(b0 + 0) * 200 + tid] = a0;
    out[(size_t)(b0 + 1) * 200 + tid] = a1;
    out[(size_t)(b0 + 2) * 200 + tid] = a2;
    out[(size_t)(b0 + 3) * 200 + tid] = a3;
  }
}

extern "C" void kernel_launch(void* const* d_in, const int* in_sizes, int n_in,
                              void* d_out, int out_size, void* d_ws, size_t ws_size,
                              hipStream_t stream)
{
  (void)in_sizes; (void)n_in; (void)out_size; (void)ws_size;
  const float* xl   = (const float*)d_in[0];
  const float* xr   = (const float*)d_in[1];
  const int*   lenl = (const int*)  d_in[2];
  const int*   lenr = (const int*)  d_in[3];
  const float* lW0  = (const float*)d_in[4];
  const float* lb0  = (const float*)d_in[5];
  const float* lW1  = (const float*)d_in[6];
  const float* lb1  = (const float*)d_in[7];
  const float* rW0  = (const float*)d_in[8];
  const float* rb0  = (const float*)d_in[9];
  const float* rW1  = (const float*)d_in[10];
  const float* rb1  = (const float*)d_in[11];
  const float* tW   = (const float*)d_in[12];
  float* out = (float*)d_out;
  char* ws = (char*)d_ws;

  constexpr size_t SZ_WXT0 = (size_t)2048 * Dp * 2;        // 1.31 MB
  constexpr size_t SZ_WT   = (size_t)2048 * 512 * 2;       // 2.10 MB
  constexpr size_t SZ_XPAD = (size_t)2 * T_ * 256 * Dp * 2; // 41.9 MB (all T, both sides)
  constexpr size_t SZ_ZP0  = (size_t)2 * MC * 2048 * 2;    // 16.8 MB per side (2 chunks)
  constexpr size_t SZ_ZP1  = (size_t)MC * 2048 * 2;        // 8.39 MB per side (1 chunk)
  constexpr size_t SZ_H0   = (size_t)TC * 256 * 512 * 2;   // 2.10 MB per side
  constexpr size_t SZ_H1   = (size_t)2 * 256 * 512 * 2;    // 0.52 MB per side
  constexpr size_t SZ_CST  = (size_t)2 * 2 * 256 * 512 * 4; // 2.10 MB
  constexpr size_t SZ_CTX  = (size_t)256 * 1024 * 4;       // 1.05 MB
  constexpr size_t SZ_FLAGS = (size_t)64 * FLAG_STRIDE * 4; // 16 KB

  size_t off = 0;
  auto carve = [&](size_t sz){ size_t o = off; off += (sz + 255) & ~(size_t)255; return o; };
  size_t o_wxt0_l = carve(SZ_WXT0), o_wxt0_r = carve(SZ_WXT0);
  size_t o_wht0_l = carve(SZ_WT),   o_wht0_r = carve(SZ_WT);
  size_t o_wxt1_l = carve(SZ_WT),   o_wxt1_r = carve(SZ_WT);
  size_t o_wht1_l = carve(SZ_WT),   o_wht1_r = carve(SZ_WT);
  size_t o_xpad   = carve(SZ_XPAD);
  size_t o_zp0_l  = carve(SZ_ZP0),  o_zp0_r  = carve(SZ_ZP0);
  size_t o_zp1_l  = carve(SZ_ZP1),  o_zp1_r  = carve(SZ_ZP1);
  size_t o_h0_l   = carve(SZ_H0),   o_h0_r   = carve(SZ_H0);
  size_t o_h1_l   = carve(SZ_H1),   o_h1_r   = carve(SZ_H1);
  size_t o_cst    = carve(SZ_CST);
  size_t o_ctx    = carve(SZ_CTX);
  size_t o_flags  = carve(SZ_FLAGS);
  // total ~116 MB

  short* wxt0_l = (short*)(ws + o_wxt0_l);
  short* wxt0_r = (short*)(ws + o_wxt0_r);
  short* wht0_l = (short*)(ws + o_wht0_l);
  short* wht0_r = (short*)(ws + o_wht0_r);
  short* wxt1_l = (short*)(ws + o_wxt1_l);
  short* wxt1_r = (short*)(ws + o_wxt1_r);
  short* wht1_l = (short*)(ws + o_wht1_l);
  short* wht1_r = (short*)(ws + o_wht1_r);
  short* xpc_l  = (short*)(ws + o_xpad);
  short* xpc_r  = xpc_l + (size_t)T_ * 256 * Dp;
  short* zp0_l  = (short*)(ws + o_zp0_l);
  short* zp0_r  = (short*)(ws + o_zp0_r);
  short* zp1_l  = (short*)(ws + o_zp1_l);
  short* zp1_r  = (short*)(ws + o_zp1_r);
  short* h0_l   = (short*)(ws + o_h0_l);
  short* h0_r   = (short*)(ws + o_h0_r);
  short* h1_l   = (short*)(ws + o_h1_l);
  short* h1_r   = (short*)(ws + o_h1_r);
  float* cst    = (float*)(ws + o_cst);
  float* ctx    = (float*)(ws + o_ctx);
  unsigned* flags = (unsigned*)(ws + o_flags);

  hipMemsetAsync(flags, 0, SZ_FLAGS, stream);

  transpose_w<<<dim3(Dp / 32, 64), 256, 0, stream>>>(lW0, wxt0_l,   0, Draw, Dp);
  transpose_w<<<dim3(Dp / 32, 64), 256, 0, stream>>>(rW0, wxt0_r,   0, Draw, Dp);
  transpose_w<<<dim3(16, 64),      256, 0, stream>>>(lW0, wht0_l, 300,  512, 512);
  transpose_w<<<dim3(16, 64),      256, 0, stream>>>(rW0, wht0_r, 300,  512, 512);
  transpose_w<<<dim3(16, 64),      256, 0, stream>>>(lW1, wxt1_l,   0,  512, 512);
  transpose_w<<<dim3(16, 64),      256, 0, stream>>>(rW1, wxt1_r,   0,  512, 512);
  transpose_w<<<dim3(16, 64),      256, 0, stream>>>(lW1, wht1_l, 512,  512, 512);
  transpose_w<<<dim3(16, 64),      256, 0, stream>>>(rW1, wht1_r, 512,  512, 512);

  // one-shot: pad/cast all of x (both sides)
  pad_x_all<<<8192, 256, 0, stream>>>(xl, xr, xpc_l);

  for(int c = 0; c < NC; c++){
    const int t0 = c * TC;
    // layer 0 GEMM, batched 2 chunks (M = 2*MC = 4096): runs on even c for (c, c+1)
    if((c & 1) == 0){
      const short* Abl = xpc_l + (size_t)t0 * 256 * Dp;
      const short* Abr = xpc_r + (size_t)t0 * 256 * Dp;
      gemm_zpre<<<dim3(2 * MC / 128, 16, 2), 256, 0, stream>>>(Abl, Abr, wxt0_l, wxt0_r,
                                                               lb0, rb0, zp0_l, zp0_r, Dp);
    }
    // layer 1: zpre1(c-1) = h0(c-1) @ Wx1 + b1 (h0 ring holds chunk c-1)
    if(c > 0)
      gemm_zpre<<<dim3(MC / 128, 16, 2), 256, 0, stream>>>(h0_l, h0_r, wxt1_l, wxt1_r,
                                                           lb1, rb1, zp1_l, zp1_r, 512);
    // dual: layer0 on chunk c || layer1 on chunk c-1; zpre0 via (c&1) pointer offset
    const size_t zoff = (size_t)(c & 1) * MC * 2048;
    lstm_rec_dual<<<256, 256, 0, stream>>>(zp0_l + zoff, zp0_r + zoff, zp1_l, zp1_r,
                                           wht0_l, wht0_r, wht1_l, wht1_r,
                                           h0_l, h0_r, h1_l, h1_r,
                                           cst, lenl, lenr, ctx, flags,
                                           t0, 1, c > 0 ? 1 : 0);
  }
  // tail: layer1 on chunk NC-1
  gemm_zpre<<<dim3(MC / 128, 16, 2), 256, 0, stream>>>(h0_l, h0_r, wxt1_l, wxt1_r,
                                                       lb1, rb1, zp1_l, zp1_r, 512);
  lstm_rec_dual<<<256, 256, 0, stream>>>(zp0_l, zp0_r, zp1_l, zp1_r,
                                         wht0_l, wht0_r, wht1_l, wht1_r,
                                         h0_l, h0_r, h1_l, h1_r,
                                         cst, lenl, lenr, ctx, flags,
                                         NC * TC, 0, 1);

  final_mm<<<64, 256, 0, stream>>>(ctx, tW, out);
}